// Round 12
// baseline (93.029 us; speedup 1.0000x reference)
//
#include <hip/hip_runtime.h>

#define B 128
#define L 1024

#if __has_builtin(__builtin_amdgcn_exp2f)
#define EXP2(x) __builtin_amdgcn_exp2f(x)
#else
#define EXP2(x) __expf((x) * 0.6931471805599453f)
#endif

// ws layout (floats):
//   [0 .. 2097152)  per-block E partials: blk*1024 + i  (2048 blocks x 4KB = 8MB)
//   [2097152]       ndcg accumulator   (zeroed by pair_kernel block 0)
//   [2097153]       completion counter (zeroed by pair_kernel block 0)
#define WS_ACC  2097152
#define WS_GCTR 2097153

// erfc(|y|) ~= exp(-(1.12838 y + 0.6446 y^2 + 0.0745 y^3)), |dPhi| <= ~2.5e-4
// (constants pre-multiplied by -log2(e) for v_exp_f32). erf(y) = copysign(1-e, y).
#define K1 -1.6279072f
#define K2 -0.9299637f
#define K3 -0.1074808f

// rotate value through a 16-lane DPP row (full-rate VALU, no LDS pipe)
__device__ __forceinline__ float ror16(float x) {
    int i = __float_as_int(x);
    i = __builtin_amdgcn_update_dpp(i, i, 0x121 /*row_ror:1*/, 0xF, 0xF, true);
    return __int_as_float(i);
}

// Antisymmetric DPP-ring pair kernel, v2 (R11 post-mortem fixes):
//  - R11 was dependency-bound: ej = ror(ej) - r made ILP=1 behind a
//    quarter-rate exp. Now TWO tiles (s, s+1) are interleaved per inner loop
//    (independent pj/ej/Ei chains -> ILP 2).
//  - Occupancy doubled: each ring's s-range split 4 ways across blocks ->
//    grid B*16 = 8 blocks/CU = 32 waves/CU.
// Tournament coverage per row (64 groups of 16):
//   qb 0-3: s=0..7 | qb 4-7: s=8..15 | qb 8-11: s=16..23
//   qb 12-13 (g<32): s=24..32 | qb 14-15 (g>=32): s=24..31
// -> every unordered group-tile exactly once (s=0 self-tile computes all
// ordered pairs internally; its ej is skipped to avoid double count).
// No atomics/fences to global in the hot path; partials plain-stored.
__global__ __launch_bounds__(256, 8) void pair_kernel(const float* __restrict__ preds,
                                                      float* __restrict__ ws) {
    __shared__ float sp[L];     // row, prescaled by 0.5 (erf argument = diff/2)
    __shared__ float ebuf[L];   // per-block E accumulation

    const int blk  = blockIdx.x;
    const int b    = blk >> 4;
    const int qb   = blk & 15;
    const int tid  = threadIdx.x;
    const int l16  = tid & 15;
    const int ring = tid >> 4;                 // 0..15
    const int g    = (qb & 3) * 16 + ring;     // this ring's i-group (0..63)
    const int base_s = (qb >> 2) * 8;          // 0,8,16,24 (block-uniform)
    const bool has32 = ((qb >> 1) == 6);       // qb 12,13 -> g<32 -> extra s=32

    if (blk == 0 && tid == 0) {
        ws[WS_ACC] = 0.0f;                     // visible to finish_kernel at
        ((int*)ws)[WS_GCTR] = 0;               // dispatch boundary
    }

    const float* prow = preds + b * L;
    float4 v = reinterpret_cast<const float4*>(prow)[tid];
    v.x *= 0.5f; v.y *= 0.5f; v.z *= 0.5f; v.w *= 0.5f;
    reinterpret_cast<float4*>(sp)[tid] = v;
    reinterpret_cast<float4*>(ebuf)[tid] = make_float4(0.f, 0.f, 0.f, 0.f);
    __syncthreads();

    const float pi = sp[g * 16 + l16];
    float Ei1 = 0.0f, Ei2 = 0.0f;

    for (int s = base_s; s < base_s + 8; s += 2) {
        const int gj1 = (g + s) & 63;
        const int gj2 = (g + s + 1) & 63;
        float pj1 = sp[gj1 * 16 + l16];
        float pj2 = sp[gj2 * 16 + l16];
        float ej1 = 0.0f, ej2 = 0.0f;
        #pragma unroll
        for (int k = 0; k < 16; ++k) {
            pj1 = ror16(pj1);                        // advance ring alignment
            pj2 = ror16(pj2);
            float d1 = pi - pj1,                  d2 = pi - pj2;
            float a1 = __builtin_fabsf(d1),       a2 = __builtin_fabsf(d2);
            float t1 = __builtin_fmaf(K3, a1, K2), t2 = __builtin_fmaf(K3, a2, K2);
            float u1 = __builtin_fmaf(t1, a1, K1), u2 = __builtin_fmaf(t2, a2, K1);
            float e1 = EXP2(a1 * u1),             e2 = EXP2(a2 * u2);
            float r1 = __builtin_copysignf(1.0f - e1, d1);
            float r2 = __builtin_copysignf(1.0f - e2, d2);
            Ei1 += r1;                            Ei2 += r2;
            ej1 = ror16(ej1) - r1;                // j-side, kept ring-aligned
            ej2 = ror16(ej2) - r2;
        }
        if (s != 0)                               // self-tile already complete in Ei
            atomicAdd(&ebuf[gj1 * 16 + l16], ej1);
        atomicAdd(&ebuf[gj2 * 16 + l16], ej2);
    }

    if (has32) {                                  // solo tail tile s=32 (g<32)
        const int gj = (g + 32) & 63;
        float pj = sp[gj * 16 + l16];
        float ej = 0.0f;
        #pragma unroll
        for (int k = 0; k < 16; ++k) {
            pj = ror16(pj);
            float d = pi - pj;
            float a = __builtin_fabsf(d);
            float t = __builtin_fmaf(K3, a, K2);
            float u = __builtin_fmaf(t, a, K1);
            float e = EXP2(a * u);
            float r = __builtin_copysignf(1.0f - e, d);
            Ei1 += r;
            ej = ror16(ej) - r;
        }
        atomicAdd(&ebuf[gj * 16 + l16], ej);
    }

    atomicAdd(&ebuf[g * 16 + l16], Ei1 + Ei2);
    __syncthreads();

    // plain coalesced store of this block's partials to its disjoint slice
    float4 r4 = reinterpret_cast<float4*>(ebuf)[tid];
    reinterpret_cast<float4*>(ws + (size_t)blk * L)[tid] = r4;
}

// grid = B blocks, 256 threads. Block b: sum the 16 E-partials per i, compute
// dcg; counting-sort IDCG (grades are ints 0..4); ndcg; last block writes out.
__global__ __launch_bounds__(256) void finish_kernel(const float* __restrict__ target,
                                                     float* __restrict__ ws,
                                                     float* __restrict__ out) {
    __shared__ unsigned long long cred[256];
    __shared__ float2 fred[256];

    const int b   = blockIdx.x;
    const int tid = threadIdx.x;
    const float* trow = target + b * L;

    float dcg_p = 0.0f;
    unsigned long long cnt = 0ull;
    #pragma unroll
    for (int k = 0; k < 4; ++k) {
        const int i = tid + k * 256;
        float E = 0.0f;
        #pragma unroll
        for (int qb = 0; qb < 16; ++qb)
            E += ws[(size_t)(b * 16 + qb) * L + i];
        // sum_j Phi = L/2 + E/2 (diag term = 0 in E, Phi(0)=0.5 exact);
        // expected_rank + 1 = 513.5 + E/2
        float er1 = 513.5f + 0.5f * E;
        float t = trow[i];
        dcg_p += (EXP2(t) - 1.0f) * __builtin_amdgcn_rcpf(__log2f(er1));
        cnt += ((unsigned long long)(t > 3.5f) << 48)
             + ((unsigned long long)(t > 2.5f) << 32)
             + ((unsigned long long)(t > 1.5f) << 16)
             + ((unsigned long long)(t > 0.5f));
    }
    cred[tid] = cnt;
    __syncthreads();
    #pragma unroll
    for (int s = 128; s > 0; s >>= 1) {
        if (tid < (unsigned)s) cred[tid] += cred[tid + s];
        __syncthreads();
    }
    const unsigned long long tot = cred[0];
    const int n4 = (int)(tot >> 48) & 0xFFFF;
    const int n3 = (int)(tot >> 32) & 0xFFFF;
    const int n2 = (int)(tot >> 16) & 0xFFFF;
    const int n1 = (int)(tot)       & 0xFFFF;

    float idcg_p = 0.0f;
    #pragma unroll
    for (int k = 0; k < 4; ++k) {
        int pos = tid + 1 + k * 256;
        float gain = (pos <= n4) ? 15.0f : (pos <= n3) ? 7.0f :
                     (pos <= n2) ? 3.0f  : (pos <= n1) ? 1.0f : 0.0f;
        idcg_p += gain * __builtin_amdgcn_rcpf(__log2f((float)pos + 1.0f));
    }
    fred[tid] = make_float2(idcg_p, dcg_p);
    __syncthreads();
    #pragma unroll
    for (int s = 128; s > 0; s >>= 1) {
        if (tid < (unsigned)s) {
            float2 x = fred[tid], y = fred[tid + s];
            fred[tid] = make_float2(x.x + y.x, x.y + y.y);
        }
        __syncthreads();
    }

    if (tid == 0) {
        float ndcg = fred[0].y / (fred[0].x + 1e-10f);
        atomicAdd(&ws[WS_ACC], ndcg);
        __threadfence();
        int old = atomicAdd((int*)ws + WS_GCTR, 1);
        if (old == B - 1) {
            float acc = atomicAdd(&ws[WS_ACC], 0.0f);  // coherent read
            out[0] = -acc * (1.0f / (float)B);
        }
    }
}

extern "C" void kernel_launch(void* const* d_in, const int* in_sizes, int n_in,
                              void* d_out, int out_size, void* d_ws, size_t ws_size,
                              hipStream_t stream) {
    const float* preds  = (const float*)d_in[0];
    const float* target = (const float*)d_in[1];
    float* out = (float*)d_out;
    float* ws  = (float*)d_ws;

    pair_kernel<<<B * 16, 256, 0, stream>>>(preds, ws);
    finish_kernel<<<B, 256, 0, stream>>>(target, ws, out);
}

// Round 13
// 88.573 us; speedup vs baseline: 1.0503x; 1.0503x over previous
//
#include <hip/hip_runtime.h>
#include <hip/hip_fp16.h>

#define B 128
#define L 1024

#if __has_builtin(__builtin_amdgcn_exp2f)
#define EXP2(x) __builtin_amdgcn_exp2f(x)
#else
#define EXP2(x) __expf((x) * 0.6931471805599453f)
#endif

typedef unsigned int uint4v __attribute__((ext_vector_type(4)));

// ws layout (floats):
//   [0..2048)  per-wave dcg partials: idx = blk*2 + wave  (blk = b*8+iseg)
//   [2048]     ndcg accumulator      (zeroed by pair_kernel block 0)
//   [2049]     completion counter    (zeroed by pair_kernel block 0)
#define WS_ACC  2048
#define WS_GCTR 2049

// erfc(|y|) ~= exp(-(1.12838 y + 0.6446 y^2 + 0.0745 y^3)), |dPhi| <= ~2.5e-4,
// y = diff/2 (prescaled into the f16 row). Constants pre-multiplied by
// -log2(e) so v_exp_f16 computes exp2 directly. Evaluated PACKED (v_pk_*_f16,
// 2 terms per full-rate slot); only the exp is per-half.
#define K1f -1.6279072f
#define K2f -0.9299637f
#define K3f -0.1074808f

// one packed evaluation: du holds 2 f16 j-values; acc += erf(y_i - y_j) x2
__device__ __forceinline__ void term2(unsigned int du, __half2 pi2,
                                      __half2 k1, __half2 k2, __half2 k3,
                                      __half2 one2, __half2& acc) {
    __half2 pj = __builtin_bit_cast(__half2, du);
    __half2 d  = __hsub2(pi2, pj);
    unsigned int dbits = __builtin_bit_cast(unsigned int, d);
    __half2 a  = __builtin_bit_cast(__half2, dbits & 0x7fff7fffu); // |d| both halves
    __half2 t  = __hfma2(k3, a, k2);
    __half2 u  = __hfma2(t,  a, k1);
    __half2 w  = __hmul2(a, u);                      // <= 0
    __half2 e  = __halves2half2(hexp2(__low2half(w)),
                                hexp2(__high2half(w)));   // ~= erfc(|y|)
    __half2 r  = __hsub2(one2, e);                   // >= 0
    unsigned int rb = __builtin_bit_cast(unsigned int, r) | (dbits & 0x80008000u);
    acc = __hadd2(acc, __builtin_bit_cast(__half2, rb));  // erf(y), signed
}

// grid = B*8 blocks, 256 threads (R8 skeleton — best measured total).
// Block (b, iseg) owns 128 i's; thread (il = tid&127, jh = tid>>7) sums its
// 512-j half from a 2KB f16 LDS row via packed f16 math. f16 accumulators
// flushed to f32 every 64 terms (|acc|<=16, rounding ~0.01 -> rank err << 1).
// NO atomics/fences in the hot path (R6 lesson); partials plain-stored.
__global__ __launch_bounds__(256, 8) void pair_kernel(const float* __restrict__ preds,
                                                      const float* __restrict__ target,
                                                      float* __restrict__ ws) {
    __shared__ __align__(16) __half sph[L];   // row * 0.5, f16
    __shared__ float red[256];                // cross-half E reduction

    const int blk  = blockIdx.x;
    const int b    = blk >> 3;
    const int iseg = blk & 7;
    const int tid  = threadIdx.x;
    const int il   = tid & 127;               // i_local
    const int jh   = tid >> 7;                // j half (0/1)

    if (blk == 0 && tid == 0) {
        ws[WS_ACC] = 0.0f;                    // visible to finish_kernel at
        ((int*)ws)[WS_GCTR] = 0;              // dispatch boundary
    }

    const float* prow = preds + b * L;

    // stage row as f16, prescaled by 0.5 (erf argument is diff/2)
    float4 v4 = reinterpret_cast<const float4*>(prow)[tid];
    __half2 h01 = __floats2half2_rn(0.5f * v4.x, 0.5f * v4.y);
    __half2 h23 = __floats2half2_rn(0.5f * v4.z, 0.5f * v4.w);
    reinterpret_cast<__half2*>(sph)[tid * 2 + 0] = h01;
    reinterpret_cast<__half2*>(sph)[tid * 2 + 1] = h23;

    const int i = iseg * 128 + il;
    const float tgt = (tid < 128) ? target[b * L + i] : 0.0f;  // hoisted

    __syncthreads();

    const __half2 pi2  = __half2half2(sph[i]);
    const __half2 k1   = __floats2half2_rn(K1f, K1f);
    const __half2 k2   = __floats2half2_rn(K2f, K2f);
    const __half2 k3   = __floats2half2_rn(K3f, K3f);
    const __half2 one2 = __floats2half2_rn(1.0f, 1.0f);
    const __half2 z2   = __floats2half2_rn(0.0f, 0.0f);

    // 512 j's = 64 uint4 chunks (each uint4 = 4 half2 = 8 terms), wave-uniform
    const uint4v* basep = reinterpret_cast<const uint4v*>(sph + jh * 512);

    float E = 0.0f;
    for (int wdw = 0; wdw < 8; ++wdw) {       // 8 windows x 64 terms
        __half2 A0 = z2, A1 = z2, A2 = z2, A3 = z2;
        #pragma unroll
        for (int m = 0; m < 8; ++m) {
            uint4v q = basep[wdw * 8 + m];
            term2(q.x, pi2, k1, k2, k3, one2, A0);
            term2(q.y, pi2, k1, k2, k3, one2, A1);
            term2(q.z, pi2, k1, k2, k3, one2, A2);
            term2(q.w, pi2, k1, k2, k3, one2, A3);
        }
        float2 f0 = __half22float2(A0);
        float2 f1 = __half22float2(A1);
        float2 f2 = __half22float2(A2);
        float2 f3 = __half22float2(A3);
        E += ((f0.x + f0.y) + (f1.x + f1.y)) + ((f2.x + f2.y) + (f3.x + f3.y));
    }

    // cross-half combine in LDS; lower 128 threads (2 waves) finish the i's
    red[tid] = E;
    __syncthreads();

    if (tid < 128) {
        float Es = red[tid] + red[tid + 128];
        // sum_j Phi = L/2 + Es/2 (diag term is exactly 0); er+1 = 513.5 + Es/2
        float er1 = 513.5f + 0.5f * Es;
        float g = EXP2(tgt) - 1.0f;           // 2^t - 1, exact for integer grades
        float contrib = g * __builtin_amdgcn_rcpf(__log2f(er1));
        #pragma unroll
        for (int off = 32; off > 0; off >>= 1)
            contrib += __shfl_down(contrib, off);
        if ((tid & 63) == 0)
            ws[blk * 2 + (tid >> 6)] = contrib;   // plain store, disjoint slot
    }
}

// grid = B blocks, 256 threads. Block b: combine 16 dcg partials, counting-sort
// IDCG (grades are ints 0..4), ndcg; last block writes the final scalar.
__global__ __launch_bounds__(256) void finish_kernel(const float* __restrict__ target,
                                                     float* __restrict__ ws,
                                                     float* __restrict__ out) {
    __shared__ unsigned long long cred[256];
    __shared__ float2 fred[256];

    const int b   = blockIdx.x;
    const int tid = threadIdx.x;
    const float* trow = target + b * L;

    // packed 16-bit counts of grades >=4,>=3,>=2,>=1 (max 1024 fits)
    unsigned long long cnt = 0ull;
    #pragma unroll
    for (int k = 0; k < 4; ++k) {
        float t = trow[tid + k * 256];
        cnt += ((unsigned long long)(t > 3.5f) << 48)
             + ((unsigned long long)(t > 2.5f) << 32)
             + ((unsigned long long)(t > 1.5f) << 16)
             + ((unsigned long long)(t > 0.5f));
    }
    cred[tid] = cnt;
    __syncthreads();
    #pragma unroll
    for (int s = 128; s > 0; s >>= 1) {
        if (tid < (unsigned)s) cred[tid] += cred[tid + s];
        __syncthreads();
    }
    unsigned long long tot = cred[0];
    const int n4 = (int)(tot >> 48) & 0xFFFF;
    const int n3 = (int)(tot >> 32) & 0xFFFF;
    const int n2 = (int)(tot >> 16) & 0xFFFF;
    const int n1 = (int)(tot)       & 0xFFFF;

    // parallel IDCG; joint reduction with the 16 dcg partials of this row
    float idcg_p = 0.0f;
    #pragma unroll
    for (int k = 0; k < 4; ++k) {
        int pos = tid + 1 + k * 256;
        float gain = (pos <= n4) ? 15.0f : (pos <= n3) ? 7.0f :
                     (pos <= n2) ? 3.0f  : (pos <= n1) ? 1.0f : 0.0f;
        idcg_p += gain * __builtin_amdgcn_rcpf(__log2f((float)pos + 1.0f));
    }
    float dcg_p = (tid < 16) ? ws[b * 16 + tid] : 0.0f;
    fred[tid] = make_float2(idcg_p, dcg_p);
    __syncthreads();
    #pragma unroll
    for (int s = 128; s > 0; s >>= 1) {
        if (tid < (unsigned)s) {
            float2 x = fred[tid], y = fred[tid + s];
            fred[tid] = make_float2(x.x + y.x, x.y + y.y);
        }
        __syncthreads();
    }

    if (tid == 0) {
        float ndcg = fred[0].y / (fred[0].x + 1e-10f);
        atomicAdd(&ws[WS_ACC], ndcg);
        __threadfence();
        int old = atomicAdd((int*)ws + WS_GCTR, 1);
        if (old == B - 1) {
            float acc = atomicAdd(&ws[WS_ACC], 0.0f);  // coherent read
            out[0] = -acc * (1.0f / (float)B);
        }
    }
}

extern "C" void kernel_launch(void* const* d_in, const int* in_sizes, int n_in,
                              void* d_out, int out_size, void* d_ws, size_t ws_size,
                              hipStream_t stream) {
    const float* preds  = (const float*)d_in[0];
    const float* target = (const float*)d_in[1];
    float* out = (float*)d_out;
    float* ws  = (float*)d_ws;

    pair_kernel<<<B * 8, 256, 0, stream>>>(preds, target, ws);
    finish_kernel<<<B, 256, 0, stream>>>(target, ws, out);
}

// Round 14
// 87.435 us; speedup vs baseline: 1.0640x; 1.0130x over previous
//
#include <hip/hip_runtime.h>
#include <hip/hip_fp16.h>

#define B 128
#define L 1024

#if __has_builtin(__builtin_amdgcn_exp2f)
#define EXP2(x) __builtin_amdgcn_exp2f(x)
#else
#define EXP2(x) __expf((x) * 0.6931471805599453f)
#endif

typedef unsigned int uint4v __attribute__((ext_vector_type(4)));

// ws layout (floats):
//   [0..2048)  per-block dcg partials: idx = b*16 + iseg
//   [2048]     ndcg accumulator      (zeroed by pair_kernel block 0)
//   [2049]     completion counter    (zeroed by pair_kernel block 0)
#define WS_ACC  2048
#define WS_GCTR 2049

// erfc(|y|) ~= exp(-(1.12838 y + 0.6446 y^2 + 0.0745 y^3)), |dPhi| <= ~2.5e-4,
// y = diff/2 (prescaled into the f16 row). Constants pre-multiplied by
// -log2(e) so v_exp_f16 computes exp2 directly. Packed v_pk_*_f16: 2 terms
// per full-rate slot; only the exp is per-half.
#define K1f -1.6279072f
#define K2f -0.9299637f
#define K3f -0.1074808f

// one packed evaluation: du holds 2 f16 j-values; acc += erf(y_i - y_j) x2
__device__ __forceinline__ void term2(unsigned int du, __half2 pi2,
                                      __half2 k1, __half2 k2, __half2 k3,
                                      __half2 one2, __half2& acc) {
    __half2 pj = __builtin_bit_cast(__half2, du);
    __half2 d  = __hsub2(pi2, pj);
    unsigned int dbits = __builtin_bit_cast(unsigned int, d);
    __half2 a  = __builtin_bit_cast(__half2, dbits & 0x7fff7fffu); // |d| both halves
    __half2 t  = __hfma2(k3, a, k2);
    __half2 u  = __hfma2(t,  a, k1);
    __half2 w  = __hmul2(a, u);                      // <= 0
    __half2 e  = __halves2half2(hexp2(__low2half(w)),
                                hexp2(__high2half(w)));   // ~= erfc(|y|)
    __half2 r  = __hsub2(one2, e);                   // >= 0
    unsigned int rb = __builtin_bit_cast(unsigned int, r) | (dbits & 0x80008000u);
    acc = __hadd2(acc, __builtin_bit_cast(__half2, rb));  // erf(y), signed
}

// grid = B*16 = 2048 blocks, 256 threads -> 8 blocks/CU -> 32 waves/CU (HW
// max; R13's 1024 blocks gave only 16 and ~55% issue efficiency on the exp
// dep-chains). Block (b, iseg) owns 64 i's; thread (il = tid&63, jq = tid>>6)
// sums its 256-j quarter from the 2KB f16 LDS row with 8 independent half2
// accumulator chains (f32 flush every window; |acc|<=8 so f16 rounding is
// negligible). j-pointer is wave-uniform. NO global atomics/fences here
// (R6 lesson); one plain partial store per block.
__global__ __launch_bounds__(256, 8) void pair_kernel(const float* __restrict__ preds,
                                                      const float* __restrict__ target,
                                                      float* __restrict__ ws) {
    __shared__ __align__(16) __half sph[L];   // row * 0.5, f16
    __shared__ float red[256];                // cross-quarter E reduction

    const int blk  = blockIdx.x;
    const int b    = blk >> 4;
    const int iseg = blk & 15;
    const int tid  = threadIdx.x;
    const int il   = tid & 63;                // i_lane
    const int jq   = tid >> 6;                // j quarter (0..3) == wave id

    if (blk == 0 && tid == 0) {
        ws[WS_ACC] = 0.0f;                    // visible to finish_kernel at
        ((int*)ws)[WS_GCTR] = 0;              // dispatch boundary
    }

    const float* prow = preds + b * L;

    // stage row as f16, prescaled by 0.5 (erf argument is diff/2)
    float4 v4 = reinterpret_cast<const float4*>(prow)[tid];
    __half2 h01 = __floats2half2_rn(0.5f * v4.x, 0.5f * v4.y);
    __half2 h23 = __floats2half2_rn(0.5f * v4.z, 0.5f * v4.w);
    reinterpret_cast<__half2*>(sph)[tid * 2 + 0] = h01;
    reinterpret_cast<__half2*>(sph)[tid * 2 + 1] = h23;

    const int i = iseg * 64 + il;
    const float tgt = (tid < 64) ? target[b * L + iseg * 64 + tid] : 0.0f;

    __syncthreads();

    const __half2 pi2  = __half2half2(sph[i]);
    const __half2 k1   = __floats2half2_rn(K1f, K1f);
    const __half2 k2   = __floats2half2_rn(K2f, K2f);
    const __half2 k3   = __floats2half2_rn(K3f, K3f);
    const __half2 one2 = __floats2half2_rn(1.0f, 1.0f);
    const __half2 z2   = __floats2half2_rn(0.0f, 0.0f);

    // this wave's j-quarter: 256 f16 = 32 uint4 (each uint4 = 8 terms)
    const uint4v* basep = reinterpret_cast<const uint4v*>(sph + jq * 256);

    float E = 0.0f;
    for (int wdw = 0; wdw < 2; ++wdw) {       // 2 windows x 128 terms
        __half2 A0 = z2, A1 = z2, A2 = z2, A3 = z2,
                A4 = z2, A5 = z2, A6 = z2, A7 = z2;
        #pragma unroll
        for (int m = 0; m < 8; ++m) {         // 2 uint4 per step, 8 chains
            uint4v q0 = basep[wdw * 16 + m * 2 + 0];
            uint4v q1 = basep[wdw * 16 + m * 2 + 1];
            term2(q0.x, pi2, k1, k2, k3, one2, A0);
            term2(q0.y, pi2, k1, k2, k3, one2, A1);
            term2(q0.z, pi2, k1, k2, k3, one2, A2);
            term2(q0.w, pi2, k1, k2, k3, one2, A3);
            term2(q1.x, pi2, k1, k2, k3, one2, A4);
            term2(q1.y, pi2, k1, k2, k3, one2, A5);
            term2(q1.z, pi2, k1, k2, k3, one2, A6);
            term2(q1.w, pi2, k1, k2, k3, one2, A7);
        }
        float2 f0 = __half22float2(A0), f1 = __half22float2(A1);
        float2 f2 = __half22float2(A2), f3 = __half22float2(A3);
        float2 f4 = __half22float2(A4), f5 = __half22float2(A5);
        float2 f6 = __half22float2(A6), f7 = __half22float2(A7);
        E += (((f0.x + f0.y) + (f1.x + f1.y)) + ((f2.x + f2.y) + (f3.x + f3.y)))
           + (((f4.x + f4.y) + (f5.x + f5.y)) + ((f6.x + f6.y) + (f7.x + f7.y)));
    }

    // cross-quarter combine in LDS; wave 0 finishes the 64 i's
    red[tid] = E;
    __syncthreads();

    if (tid < 64) {
        float Es = (red[tid] + red[tid + 64]) + (red[tid + 128] + red[tid + 192]);
        // sum_j Phi = L/2 + Es/2 (diag term is exactly 0); er+1 = 513.5 + Es/2
        float er1 = 513.5f + 0.5f * Es;
        float g = EXP2(tgt) - 1.0f;           // 2^t - 1, exact for integer grades
        float contrib = g * __builtin_amdgcn_rcpf(__log2f(er1));
        #pragma unroll
        for (int off = 32; off > 0; off >>= 1)
            contrib += __shfl_down(contrib, off);
        if (tid == 0)
            ws[blk] = contrib;                // plain store, disjoint slot
    }
}

// grid = B blocks, 256 threads. Block b: combine 16 dcg partials, counting-sort
// IDCG (grades are ints 0..4), ndcg; last block writes the final scalar.
__global__ __launch_bounds__(256) void finish_kernel(const float* __restrict__ target,
                                                     float* __restrict__ ws,
                                                     float* __restrict__ out) {
    __shared__ unsigned long long cred[256];
    __shared__ float2 fred[256];

    const int b   = blockIdx.x;
    const int tid = threadIdx.x;
    const float* trow = target + b * L;

    // packed 16-bit counts of grades >=4,>=3,>=2,>=1 (max 1024 fits)
    unsigned long long cnt = 0ull;
    #pragma unroll
    for (int k = 0; k < 4; ++k) {
        float t = trow[tid + k * 256];
        cnt += ((unsigned long long)(t > 3.5f) << 48)
             + ((unsigned long long)(t > 2.5f) << 32)
             + ((unsigned long long)(t > 1.5f) << 16)
             + ((unsigned long long)(t > 0.5f));
    }
    cred[tid] = cnt;
    __syncthreads();
    #pragma unroll
    for (int s = 128; s > 0; s >>= 1) {
        if (tid < (unsigned)s) cred[tid] += cred[tid + s];
        __syncthreads();
    }
    unsigned long long tot = cred[0];
    const int n4 = (int)(tot >> 48) & 0xFFFF;
    const int n3 = (int)(tot >> 32) & 0xFFFF;
    const int n2 = (int)(tot >> 16) & 0xFFFF;
    const int n1 = (int)(tot)       & 0xFFFF;

    // parallel IDCG; joint reduction with the 16 dcg partials of this row
    float idcg_p = 0.0f;
    #pragma unroll
    for (int k = 0; k < 4; ++k) {
        int pos = tid + 1 + k * 256;
        float gain = (pos <= n4) ? 15.0f : (pos <= n3) ? 7.0f :
                     (pos <= n2) ? 3.0f  : (pos <= n1) ? 1.0f : 0.0f;
        idcg_p += gain * __builtin_amdgcn_rcpf(__log2f((float)pos + 1.0f));
    }
    float dcg_p = (tid < 16) ? ws[b * 16 + tid] : 0.0f;
    fred[tid] = make_float2(idcg_p, dcg_p);
    __syncthreads();
    #pragma unroll
    for (int s = 128; s > 0; s >>= 1) {
        if (tid < (unsigned)s) {
            float2 x = fred[tid], y = fred[tid + s];
            fred[tid] = make_float2(x.x + y.x, x.y + y.y);
        }
        __syncthreads();
    }

    if (tid == 0) {
        float ndcg = fred[0].y / (fred[0].x + 1e-10f);
        atomicAdd(&ws[WS_ACC], ndcg);
        __threadfence();
        int old = atomicAdd((int*)ws + WS_GCTR, 1);
        if (old == B - 1) {
            float acc = atomicAdd(&ws[WS_ACC], 0.0f);  // coherent read
            out[0] = -acc * (1.0f / (float)B);
        }
    }
}

extern "C" void kernel_launch(void* const* d_in, const int* in_sizes, int n_in,
                              void* d_out, int out_size, void* d_ws, size_t ws_size,
                              hipStream_t stream) {
    const float* preds  = (const float*)d_in[0];
    const float* target = (const float*)d_in[1];
    float* out = (float*)d_out;
    float* ws  = (float*)d_ws;

    pair_kernel<<<B * 16, 256, 0, stream>>>(preds, target, ws);
    finish_kernel<<<B, 256, 0, stream>>>(target, ws, out);
}